// Round 2
// baseline (479.782 us; speedup 1.0000x reference)
//
#include <hip/hip_runtime.h>

#define T_DIM 256
#define B_DIM 2048
#define D_IN_DIM 128
#define NQ 8
#define ROWS_PER_BLK 128
#define TSTRIDE 33    // transpose tile pad: 2-way, free

// LDS X tile: [128][128] floats, XOR-swizzled columns. Element (row,k) at
// row*128 + (k ^ (row&31)).  Read (uniform k, row=lane): bank =
// (k ^ (lane&31)) % 32 -> lanes l and l+32 share a bank -> 2-way, free.
// (Round 1 bug: XSTRIDE=127 < row length 128 -> rows overlapped -> absmax 0.21.)
#define XSIDX(row, k) (((row) << 7) + ((k) ^ ((row) & 31)))

// ---------------------------------------------------------------------------
// Kernel 1: Z[row][q] = float4(f,i,g,o) of x[row].W[:,q] + b[q] + th[q]
// 128-row tile, 2 rows per lane: each pair of wave-uniform float4 W fetches
// (scalarizable to s_load_dwordx4) feeds 16 FMAs.
// ---------------------------------------------------------------------------
__global__ __launch_bounds__(256) void qlstm_gemm(
    const float* __restrict__ X,   // chunk base, [rows][128]
    const float* __restrict__ Wf, const float* __restrict__ Wi,
    const float* __restrict__ Wg, const float* __restrict__ Wo,
    const float* __restrict__ bf, const float* __restrict__ bi,
    const float* __restrict__ bg, const float* __restrict__ bo,
    const float* __restrict__ thf, const float* __restrict__ thi,
    const float* __restrict__ thg, const float* __restrict__ tho,
    float4* __restrict__ Z)        // [rows][8] float4
{
    __shared__ float xs[ROWS_PER_BLK * D_IN_DIM];   // 64 KiB, reused for transpose

    const int t = (int)threadIdx.x;
    const int r0 = (int)blockIdx.x * ROWS_PER_BLK;

    // Stage X tile: 128 rows x 128 floats = 4096 float4, 16 per thread, coalesced.
    const float4* Xg = (const float4*)(X + (size_t)r0 * D_IN_DIM);
#pragma unroll
    for (int i = 0; i < 16; i++) {
        int L = t + i * 256;
        float4 v = Xg[L];
        int row = L >> 5;          // 32 float4 per row
        int k0  = (L & 31) * 4;
        xs[XSIDX(row, k0 + 0)] = v.x;
        xs[XSIDX(row, k0 + 1)] = v.y;
        xs[XSIDX(row, k0 + 2)] = v.z;
        xs[XSIDX(row, k0 + 3)] = v.w;
    }
    __syncthreads();

    const int wid  = __builtin_amdgcn_readfirstlane(t >> 6);  // wave id = gate
    const int lane = t & 63;                                   // rows lane, lane+64

    const float* W  = (wid == 0) ? Wf  : (wid == 1) ? Wi  : (wid == 2) ? Wg  : Wo;
    const float* BB = (wid == 0) ? bf  : (wid == 1) ? bi  : (wid == 2) ? bg  : bo;
    const float* TH = (wid == 0) ? thf : (wid == 1) ? thi : (wid == 2) ? thg : tho;
    const float4* __restrict__ W4 = (const float4*)W;

    float acc0[NQ], acc1[NQ];
#pragma unroll
    for (int q = 0; q < NQ; q++) { float b0 = BB[q] + TH[q]; acc0[q] = b0; acc1[q] = b0; }

    const float* xr0 = &xs[(size_t)lane << 7];
    const float* xr1 = &xs[(size_t)(lane + 64) << 7];
    const int sw = lane & 31;      // same swizzle for row lane and lane+64
#pragma unroll 4
    for (int k = 0; k < D_IN_DIM; k++) {
        float x0 = xr0[k ^ sw];
        float x1 = xr1[k ^ sw];
        float4 wa = W4[2 * k];
        float4 wb = W4[2 * k + 1];
        acc0[0] += x0 * wa.x; acc0[1] += x0 * wa.y; acc0[2] += x0 * wa.z; acc0[3] += x0 * wa.w;
        acc0[4] += x0 * wb.x; acc0[5] += x0 * wb.y; acc0[6] += x0 * wb.z; acc0[7] += x0 * wb.w;
        acc1[0] += x1 * wa.x; acc1[1] += x1 * wa.y; acc1[2] += x1 * wa.z; acc1[3] += x1 * wa.w;
        acc1[4] += x1 * wb.x; acc1[5] += x1 * wb.y; acc1[6] += x1 * wb.z; acc1[7] += x1 * wb.w;
    }

    __syncthreads();
    float* tile = xs;   // [128][TSTRIDE], elem (r, q*4+gate)
#pragma unroll
    for (int q = 0; q < NQ; q++) {
        tile[lane * TSTRIDE + q * 4 + wid] = acc0[q];
        tile[(lane + 64) * TSTRIDE + q * 4 + wid] = acc1[q];
    }
    __syncthreads();

    float4* Zblk = Z + (size_t)r0 * NQ;
#pragma unroll
    for (int i = 0; i < 4; i++) {
        int F = t + i * 256;          // float4 index: r = F>>3, q = F&7
        int r = F >> 3, q = F & 7;
        const float* s = &tile[r * TSTRIDE + q * 4];
        Zblk[F] = make_float4(s[0], s[1], s[2], s[3]);
    }
}

// ---------------------------------------------------------------------------
// Kernel 2: sequential recurrence. 256 blocks x 64 thr (1 wave/CU).
// Per-step global store removed from the dependency chain: each step writes a
// dedicated hout[s] register; the 8 stores are batched after the next
// prefetch issue, so no s_waitcnt ever lands on a young VMEM op and the
// 8-deep prefetch stays 8-deep (vmcnt retires in order). Gate dots split
// into two 4-deep FMA chains.
// ---------------------------------------------------------------------------
#define INV_2PI 0.15915494309189535f
#define L2E     1.4426950408889634f

__device__ __forceinline__ float hw_cos(float x) {
    return __builtin_amdgcn_cosf(x * INV_2PI);        // v_cos takes revolutions
}
__device__ __forceinline__ float hw_sig(float x) {
    return __builtin_amdgcn_rcpf(1.0f + __builtin_amdgcn_exp2f(-L2E * x));
}
__device__ __forceinline__ float hw_tanh(float x) {
    return 1.0f - 2.0f * __builtin_amdgcn_rcpf(__builtin_amdgcn_exp2f((2.0f * L2E) * x) + 1.0f);
}

#define BCAST8(x, J) \
    __int_as_float(__builtin_amdgcn_ds_swizzle(__float_as_int(x), ((J) << 5) | 0x18))

// Two 4-deep FMA chains per gate (halves dot-product latency vs 8-deep).
#define LSTM_STEP_R(zv, hdst) { \
    float h0 = BCAST8(h, 0), h1 = BCAST8(h, 1), h2 = BCAST8(h, 2), h3 = BCAST8(h, 3); \
    float h4 = BCAST8(h, 4), h5 = BCAST8(h, 5), h6 = BCAST8(h, 6), h7 = BCAST8(h, 7); \
    float f0 = fmaf(h0, whf[0], (zv).x), f1 = fmaf(h1, whf[1], 0.0f); \
    float i0 = fmaf(h0, whi[0], (zv).y), i1 = fmaf(h1, whi[1], 0.0f); \
    float g0 = fmaf(h0, whg[0], (zv).z), g1 = fmaf(h1, whg[1], 0.0f); \
    float o0 = fmaf(h0, who[0], (zv).w), o1 = fmaf(h1, who[1], 0.0f); \
    f0 = fmaf(h2, whf[2], f0); f1 = fmaf(h3, whf[3], f1); \
    i0 = fmaf(h2, whi[2], i0); i1 = fmaf(h3, whi[3], i1); \
    g0 = fmaf(h2, whg[2], g0); g1 = fmaf(h3, whg[3], g1); \
    o0 = fmaf(h2, who[2], o0); o1 = fmaf(h3, who[3], o1); \
    f0 = fmaf(h4, whf[4], f0); f1 = fmaf(h5, whf[5], f1); \
    i0 = fmaf(h4, whi[4], i0); i1 = fmaf(h5, whi[5], i1); \
    g0 = fmaf(h4, whg[4], g0); g1 = fmaf(h5, whg[5], g1); \
    o0 = fmaf(h4, who[4], o0); o1 = fmaf(h5, who[5], o1); \
    f0 = fmaf(h6, whf[6], f0); f1 = fmaf(h7, whf[7], f1); \
    i0 = fmaf(h6, whi[6], i0); i1 = fmaf(h7, whi[7], i1); \
    g0 = fmaf(h6, whg[6], g0); g1 = fmaf(h7, whg[7], g1); \
    o0 = fmaf(h6, who[6], o0); o1 = fmaf(h7, who[7], o1); \
    float fg = hw_sig(hw_cos(f0 + f1)); \
    float ig = hw_sig(hw_cos(i0 + i1)); \
    float gg = hw_tanh(hw_cos(g0 + g1)); \
    float og = hw_sig(hw_cos(o0 + o1)); \
    c = fmaf(fg, c, ig * gg); \
    h = og * hw_tanh(c); \
    (hdst) = h; }

__global__ __launch_bounds__(64) void qlstm_recur(
    const float4* __restrict__ Z,  // chunk base, [ct][B*NQ] float4
    const float* __restrict__ Wf, const float* __restrict__ Wi,
    const float* __restrict__ Wg, const float* __restrict__ Wo,
    float* __restrict__ out,       // full output base
    float* __restrict__ state,     // [h: B*8][c: B*8]
    int t0, int ct, int first, int last)
{
    const int tid = (int)blockIdx.x * 64 + (int)threadIdx.x;  // 0..16383
    const int q   = tid & 7;

    float whf[8], whi[8], whg[8], who[8];
#pragma unroll
    for (int j = 0; j < 8; j++) {
        whf[j] = Wf[(D_IN_DIM + j) * NQ + q];
        whi[j] = Wi[(D_IN_DIM + j) * NQ + q];
        whg[j] = Wg[(D_IN_DIM + j) * NQ + q];
        who[j] = Wo[(D_IN_DIM + j) * NQ + q];
    }

    float h, c;
    if (first) { h = 0.0f; c = 0.0f; }
    else       { h = state[tid]; c = state[B_DIM * NQ + tid]; }

    const size_t stepsz = (size_t)B_DIM * NQ;   // 16384
    const float4* Zp = Z + tid;
    float* og_ptr = out + (size_t)t0 * stepsz + tid;

    float4 bufA[8], bufB[8];
    float houtA[8], houtB[8];
    // Prologue: fill A with steps 0..7 (ct is a multiple of 16, >= 16).
#pragma unroll
    for (int s = 0; s < 8; s++) bufA[s] = Zp[(size_t)s * stepsz];

    for (int tb = 0; tb < ct; tb += 16) {
        // Issue loads for steps tb+8..tb+15 into B.
#pragma unroll
        for (int s = 0; s < 8; s++) bufB[s] = Zp[(size_t)(tb + 8 + s) * stepsz];
        __builtin_amdgcn_sched_barrier(0);   // pin: loads stay issued here
        // Consume A: steps tb..tb+7 -> dedicated hout registers, NO stores.
#pragma unroll
        for (int s = 0; s < 8; s++) {
            float4 z = bufA[s];
            LSTM_STEP_R(z, houtA[s])
        }
        // Issue loads for steps tb+16..tb+23 into A (skip on last group).
        if (tb + 16 < ct) {
#pragma unroll
            for (int s = 0; s < 8; s++) bufA[s] = Zp[(size_t)(tb + 16 + s) * stepsz];
        }
        __builtin_amdgcn_sched_barrier(0);
        // Batched stores of A-group outputs (registers rewritten >=16 steps later).
#pragma unroll
        for (int s = 0; s < 8; s++) og_ptr[(size_t)s * stepsz] = houtA[s];
        // Consume B: steps tb+8..tb+15.
#pragma unroll
        for (int s = 0; s < 8; s++) {
            float4 z = bufB[s];
            LSTM_STEP_R(z, houtB[s])
        }
        // Batched stores of B-group outputs.
#pragma unroll
        for (int s = 0; s < 8; s++) og_ptr[(size_t)(8 + s) * stepsz] = houtB[s];
        og_ptr += (size_t)16 * stepsz;
    }

    if (last) {
        out[(size_t)T_DIM * stepsz + tid] = h;
        out[(size_t)T_DIM * stepsz + stepsz + tid] = c;
    } else {
        state[tid] = h;
        state[B_DIM * NQ + tid] = c;
    }
}

// ---------------------------------------------------------------------------
extern "C" void kernel_launch(void* const* d_in, const int* in_sizes, int n_in,
                              void* d_out, int out_size, void* d_ws, size_t ws_size,
                              hipStream_t stream) {
    const float* X   = (const float*)d_in[0];
    const float* Wf  = (const float*)d_in[1];
    const float* bf  = (const float*)d_in[2];
    const float* Wi  = (const float*)d_in[3];
    const float* bi  = (const float*)d_in[4];
    const float* Wg  = (const float*)d_in[5];
    const float* bg  = (const float*)d_in[6];
    const float* Wo  = (const float*)d_in[7];
    const float* bo  = (const float*)d_in[8];
    const float* thf = (const float*)d_in[9];
    const float* thi = (const float*)d_in[10];
    const float* thg = (const float*)d_in[11];
    const float* tho = (const float*)d_in[12];
    float* out = (float*)d_out;

    const size_t state_bytes = (size_t)2 * B_DIM * NQ * sizeof(float);  // 128 KiB
    float* state = (float*)d_ws;
    float4* Zbuf = (float4*)((char*)d_ws + state_bytes);
    size_t avail = ws_size > state_bytes ? ws_size - state_bytes : 0;
    const size_t z_bytes_per_t = (size_t)B_DIM * NQ * sizeof(float4);   // 256 KiB
    int maxChunkT = (int)(avail / z_bytes_per_t);
    if (maxChunkT > T_DIM) maxChunkT = T_DIM;
    maxChunkT &= ~15;                  // recur requires multiples of 16
    if (maxChunkT < 16) maxChunkT = 16; // ws assumed >= ~4.2 MiB

    int t0 = 0;
    int first = 1;
    while (t0 < T_DIM) {
        int ct = (T_DIM - t0 < maxChunkT) ? (T_DIM - t0) : maxChunkT;
        int rows = ct * B_DIM;
        qlstm_gemm<<<rows / ROWS_PER_BLK, 256, 0, stream>>>(
            X + (size_t)t0 * B_DIM * D_IN_DIM,
            Wf, Wi, Wg, Wo, bf, bi, bg, bo, thf, thi, thg, tho,
            Zbuf);
        int last = (t0 + ct == T_DIM) ? 1 : 0;
        qlstm_recur<<<(B_DIM * NQ) / 64, 64, 0, stream>>>(
            Zbuf, Wf, Wi, Wg, Wo, out, state, t0, ct, first, last);
        t0 += ct;
        first = 0;
    }
}

// Round 3
// 443.675 us; speedup vs baseline: 1.0814x; 1.0814x over previous
//
#include <hip/hip_runtime.h>

#define T_DIM 256
#define B_DIM 2048
#define D_IN_DIM 128
#define NQ 8
#define ROWS_PER_BLK 64
#define XSTRIDE 129   // X tile pad: read bank = (lane + k) % 32 -> 2-way, free
#define TSTRIDE 33    // transpose tile pad: 2-way, free

// ---------------------------------------------------------------------------
// Kernel 1: Z[row][q] = float4(f,i,g,o) of x[row].W[:,q] + b[q] + th[q]
// THIS ROUND: W staged in LDS (removes dependence on compiler scalarizing the
// wave-uniform W stream -- if that s_load promotion failed, the k-loop was
// VMEM-issue-bound at ~150us, matching both prior rounds). Inner loop is now
// pure LDS + VALU: per k, 1 ds_read_b32 (x; lanes l/l+32 2-way = free) +
// 2 broadcast ds_read_b128 (w; all lanes same addr = conflict-free) +
// 8 v_fmac. 64-row tile, staging/epilogue identical to the known-good R0.
// ---------------------------------------------------------------------------
__global__ __launch_bounds__(256) void qlstm_gemm(
    const float* __restrict__ X,   // chunk base, [rows][128]
    const float* __restrict__ Wf, const float* __restrict__ Wi,
    const float* __restrict__ Wg, const float* __restrict__ Wo,
    const float* __restrict__ bf, const float* __restrict__ bi,
    const float* __restrict__ bg, const float* __restrict__ bo,
    const float* __restrict__ thf, const float* __restrict__ thi,
    const float* __restrict__ thg, const float* __restrict__ tho,
    float4* __restrict__ Z)        // [rows][8] float4
{
    __shared__ float xs[ROWS_PER_BLK * XSTRIDE];   // 33 KB, reused for transpose
    __shared__ float wsh[4 * D_IN_DIM * NQ];       // 16 KB: [gate][k][q]

    const int t = (int)threadIdx.x;
    const int r0 = (int)blockIdx.x * ROWS_PER_BLK;

    const int wid  = __builtin_amdgcn_readfirstlane(t >> 6);  // wave id = gate
    const int lane = t & 63;                                   // row in tile

    const float* W  = (wid == 0) ? Wf  : (wid == 1) ? Wi  : (wid == 2) ? Wg  : Wo;
    const float* BB = (wid == 0) ? bf  : (wid == 1) ? bi  : (wid == 2) ? bg  : bo;
    const float* TH = (wid == 0) ? thf : (wid == 1) ? thi : (wid == 2) ? thg : tho;

    // Stage this wave's gate weights: first 1024 floats of W (rows 0..127) in
    // [k][q] layout (same as global) -> wsh[wid*1024 + k*8 + q].
    {
        const float4* Wg4 = (const float4*)W;            // 256 float4
        float4* wd = (float4*)&wsh[wid * (D_IN_DIM * NQ)];
#pragma unroll
        for (int j = 0; j < 4; j++) wd[j * 64 + lane] = Wg4[j * 64 + lane];
    }

    // Stage X tile: 64 rows x 128 floats = 2048 float4, 8 per thread, coalesced.
    const float4* Xg = (const float4*)(X + (size_t)r0 * D_IN_DIM);
#pragma unroll
    for (int i = 0; i < 8; i++) {
        int L = t + i * 256;
        float4 v = Xg[L];
        int row = L >> 5;          // 32 float4 per row
        int k4  = L & 31;
        float* d = &xs[row * XSTRIDE + k4 * 4];
        d[0] = v.x; d[1] = v.y; d[2] = v.z; d[3] = v.w;
    }
    __syncthreads();

    float acc[NQ];
#pragma unroll
    for (int q = 0; q < NQ; q++) acc[q] = BB[q] + TH[q];

    const float*  xrow = &xs[lane * XSTRIDE];
    const float4* wk   = (const float4*)&wsh[wid * (D_IN_DIM * NQ)];
#pragma unroll 4
    for (int k = 0; k < D_IN_DIM; k++) {
        float xk = xrow[k];
        float4 wa = wk[2 * k];       // w[k][0..3], all lanes same addr (bcast)
        float4 wb = wk[2 * k + 1];   // w[k][4..7]
        acc[0] += xk * wa.x; acc[1] += xk * wa.y; acc[2] += xk * wa.z; acc[3] += xk * wa.w;
        acc[4] += xk * wb.x; acc[5] += xk * wb.y; acc[6] += xk * wb.z; acc[7] += xk * wb.w;
    }

    __syncthreads();
    float* tile = xs;   // [64][TSTRIDE], elem (r, q*4+gate)
#pragma unroll
    for (int q = 0; q < NQ; q++)
        tile[lane * TSTRIDE + q * 4 + wid] = acc[q];
    __syncthreads();

    float4* Zblk = Z + (size_t)r0 * NQ;
#pragma unroll
    for (int i = 0; i < 2; i++) {
        int F = t + i * 256;          // float4 index: r = F>>3, q = F&7
        int r = F >> 3, q = F & 7;
        const float* s = &tile[r * TSTRIDE + q * 4];
        Zblk[F] = make_float4(s[0], s[1], s[2], s[3]);
    }
}

// ---------------------------------------------------------------------------
// Kernel 2: sequential recurrence. 256 blocks x 64 thr (1 wave/CU).
// UNCHANGED from round-2 passing version (attribution: this round only the
// GEMM changed).
// ---------------------------------------------------------------------------
#define INV_2PI 0.15915494309189535f
#define L2E     1.4426950408889634f

__device__ __forceinline__ float hw_cos(float x) {
    return __builtin_amdgcn_cosf(x * INV_2PI);        // v_cos takes revolutions
}
__device__ __forceinline__ float hw_sig(float x) {
    return __builtin_amdgcn_rcpf(1.0f + __builtin_amdgcn_exp2f(-L2E * x));
}
__device__ __forceinline__ float hw_tanh(float x) {
    return 1.0f - 2.0f * __builtin_amdgcn_rcpf(__builtin_amdgcn_exp2f((2.0f * L2E) * x) + 1.0f);
}

#define BCAST8(x, J) \
    __int_as_float(__builtin_amdgcn_ds_swizzle(__float_as_int(x), ((J) << 5) | 0x18))

// Two 4-deep FMA chains per gate (halves dot-product latency vs 8-deep).
#define LSTM_STEP_R(zv, hdst) { \
    float h0 = BCAST8(h, 0), h1 = BCAST8(h, 1), h2 = BCAST8(h, 2), h3 = BCAST8(h, 3); \
    float h4 = BCAST8(h, 4), h5 = BCAST8(h, 5), h6 = BCAST8(h, 6), h7 = BCAST8(h, 7); \
    float f0 = fmaf(h0, whf[0], (zv).x), f1 = fmaf(h1, whf[1], 0.0f); \
    float i0 = fmaf(h0, whi[0], (zv).y), i1 = fmaf(h1, whi[1], 0.0f); \
    float g0 = fmaf(h0, whg[0], (zv).z), g1 = fmaf(h1, whg[1], 0.0f); \
    float o0 = fmaf(h0, who[0], (zv).w), o1 = fmaf(h1, who[1], 0.0f); \
    f0 = fmaf(h2, whf[2], f0); f1 = fmaf(h3, whf[3], f1); \
    i0 = fmaf(h2, whi[2], i0); i1 = fmaf(h3, whi[3], i1); \
    g0 = fmaf(h2, whg[2], g0); g1 = fmaf(h3, whg[3], g1); \
    o0 = fmaf(h2, who[2], o0); o1 = fmaf(h3, who[3], o1); \
    f0 = fmaf(h4, whf[4], f0); f1 = fmaf(h5, whf[5], f1); \
    i0 = fmaf(h4, whi[4], i0); i1 = fmaf(h5, whi[5], i1); \
    g0 = fmaf(h4, whg[4], g0); g1 = fmaf(h5, whg[5], g1); \
    o0 = fmaf(h4, who[4], o0); o1 = fmaf(h5, who[5], o1); \
    f0 = fmaf(h6, whf[6], f0); f1 = fmaf(h7, whf[7], f1); \
    i0 = fmaf(h6, whi[6], i0); i1 = fmaf(h7, whi[7], i1); \
    g0 = fmaf(h6, whg[6], g0); g1 = fmaf(h7, whg[7], g1); \
    o0 = fmaf(h6, who[6], o0); o1 = fmaf(h7, who[7], o1); \
    float fg = hw_sig(hw_cos(f0 + f1)); \
    float ig = hw_sig(hw_cos(i0 + i1)); \
    float gg = hw_tanh(hw_cos(g0 + g1)); \
    float og = hw_sig(hw_cos(o0 + o1)); \
    c = fmaf(fg, c, ig * gg); \
    h = og * hw_tanh(c); \
    (hdst) = h; }

__global__ __launch_bounds__(64) void qlstm_recur(
    const float4* __restrict__ Z,  // chunk base, [ct][B*NQ] float4
    const float* __restrict__ Wf, const float* __restrict__ Wi,
    const float* __restrict__ Wg, const float* __restrict__ Wo,
    float* __restrict__ out,       // full output base
    float* __restrict__ state,     // [h: B*8][c: B*8]
    int t0, int ct, int first, int last)
{
    const int tid = (int)blockIdx.x * 64 + (int)threadIdx.x;  // 0..16383
    const int q   = tid & 7;

    float whf[8], whi[8], whg[8], who[8];
#pragma unroll
    for (int j = 0; j < 8; j++) {
        whf[j] = Wf[(D_IN_DIM + j) * NQ + q];
        whi[j] = Wi[(D_IN_DIM + j) * NQ + q];
        whg[j] = Wg[(D_IN_DIM + j) * NQ + q];
        who[j] = Wo[(D_IN_DIM + j) * NQ + q];
    }

    float h, c;
    if (first) { h = 0.0f; c = 0.0f; }
    else       { h = state[tid]; c = state[B_DIM * NQ + tid]; }

    const size_t stepsz = (size_t)B_DIM * NQ;   // 16384
    const float4* Zp = Z + tid;
    float* og_ptr = out + (size_t)t0 * stepsz + tid;

    float4 bufA[8], bufB[8];
    float houtA[8], houtB[8];
    // Prologue: fill A with steps 0..7 (ct is a multiple of 16, >= 16).
#pragma unroll
    for (int s = 0; s < 8; s++) bufA[s] = Zp[(size_t)s * stepsz];

    for (int tb = 0; tb < ct; tb += 16) {
        // Issue loads for steps tb+8..tb+15 into B.
#pragma unroll
        for (int s = 0; s < 8; s++) bufB[s] = Zp[(size_t)(tb + 8 + s) * stepsz];
        __builtin_amdgcn_sched_barrier(0);   // pin: loads stay issued here
        // Consume A: steps tb..tb+7 -> dedicated hout registers, NO stores.
#pragma unroll
        for (int s = 0; s < 8; s++) {
            float4 z = bufA[s];
            LSTM_STEP_R(z, houtA[s])
        }
        // Issue loads for steps tb+16..tb+23 into A (skip on last group).
        if (tb + 16 < ct) {
#pragma unroll
            for (int s = 0; s < 8; s++) bufA[s] = Zp[(size_t)(tb + 16 + s) * stepsz];
        }
        __builtin_amdgcn_sched_barrier(0);
        // Batched stores of A-group outputs (registers rewritten >=16 steps later).
#pragma unroll
        for (int s = 0; s < 8; s++) og_ptr[(size_t)s * stepsz] = houtA[s];
        // Consume B: steps tb+8..tb+15.
#pragma unroll
        for (int s = 0; s < 8; s++) {
            float4 z = bufB[s];
            LSTM_STEP_R(z, houtB[s])
        }
        // Batched stores of B-group outputs.
#pragma unroll
        for (int s = 0; s < 8; s++) og_ptr[(size_t)(8 + s) * stepsz] = houtB[s];
        og_ptr += (size_t)16 * stepsz;
    }

    if (last) {
        out[(size_t)T_DIM * stepsz + tid] = h;
        out[(size_t)T_DIM * stepsz + stepsz + tid] = c;
    } else {
        state[tid] = h;
        state[B_DIM * NQ + tid] = c;
    }
}

// ---------------------------------------------------------------------------
extern "C" void kernel_launch(void* const* d_in, const int* in_sizes, int n_in,
                              void* d_out, int out_size, void* d_ws, size_t ws_size,
                              hipStream_t stream) {
    const float* X   = (const float*)d_in[0];
    const float* Wf  = (const float*)d_in[1];
    const float* bf  = (const float*)d_in[2];
    const float* Wi  = (const float*)d_in[3];
    const float* bi  = (const float*)d_in[4];
    const float* Wg  = (const float*)d_in[5];
    const float* bg  = (const float*)d_in[6];
    const float* Wo  = (const float*)d_in[7];
    const float* bo  = (const float*)d_in[8];
    const float* thf = (const float*)d_in[9];
    const float* thi = (const float*)d_in[10];
    const float* thg = (const float*)d_in[11];
    const float* tho = (const float*)d_in[12];
    float* out = (float*)d_out;

    const size_t state_bytes = (size_t)2 * B_DIM * NQ * sizeof(float);  // 128 KiB
    float* state = (float*)d_ws;
    float4* Zbuf = (float4*)((char*)d_ws + state_bytes);
    size_t avail = ws_size > state_bytes ? ws_size - state_bytes : 0;
    const size_t z_bytes_per_t = (size_t)B_DIM * NQ * sizeof(float4);   // 256 KiB
    int maxChunkT = (int)(avail / z_bytes_per_t);
    if (maxChunkT > T_DIM) maxChunkT = T_DIM;
    maxChunkT &= ~15;                  // recur requires multiples of 16
    if (maxChunkT < 16) maxChunkT = 16; // ws assumed >= ~4.2 MiB

    int t0 = 0;
    int first = 1;
    while (t0 < T_DIM) {
        int ct = (T_DIM - t0 < maxChunkT) ? (T_DIM - t0) : maxChunkT;
        int rows = ct * B_DIM;
        qlstm_gemm<<<rows / ROWS_PER_BLK, 256, 0, stream>>>(
            X + (size_t)t0 * B_DIM * D_IN_DIM,
            Wf, Wi, Wg, Wo, bf, bi, bg, bo, thf, thi, thg, tho,
            Zbuf);
        int last = (t0 + ct == T_DIM) ? 1 : 0;
        qlstm_recur<<<(B_DIM * NQ) / 64, 64, 0, stream>>>(
            Zbuf, Wf, Wi, Wg, Wo, out, state, t0, ct, first, last);
        t0 += ct;
        first = 0;
    }
}